// Round 5
// baseline (182.412 us; speedup 1.0000x reference)
//
#include <hip/hip_runtime.h>
#include <math.h>

#define NN   10000
#define DEG  16
#define SS   128
#define NRBF 20
#define GG   64
#define RC   10.0f
#define PI_F 3.14159265358979323846f
#define NB   16
#define TPB  512

__device__ __forceinline__ float silu_f(float x){
    return x / (1.0f + __expf(-x));
}

// ---------------------------------------------------------------------------
// Kernel 1a: h = silu(s0 @ phi_w1 + b1)  (s0 uniform). Also zeroes gs.
// ---------------------------------------------------------------------------
__global__ __launch_bounds__(256) void k_phi1(
    const float* __restrict__ emb0,
    const float* __restrict__ w1, const float* __restrict__ b1,
    float* __restrict__ phiH, float* __restrict__ gs){
    __shared__ float s0[SS];
    __shared__ float part[2][SS];
    int t = threadIdx.x;
    for (int i = t; i < GG*SS; i += 256) gs[i] = 0.0f;
    if (t < SS) s0[t] = 128.0f * emb0[t];
    __syncthreads();
    int c = t & 127, half = t >> 7;
    float acc = 0.0f;
    int s0i = half * 64;
    #pragma unroll 8
    for (int s = 0; s < 64; s++)
        acc = fmaf(s0[s0i + s], w1[(s0i + s)*SS + c], acc);
    part[half][c] = acc;
    __syncthreads();
    if (t < SS) phiH[t] = silu_f(b1[t] + part[0][t] + part[1][t]);
}

// ---------------------------------------------------------------------------
// Kernel 1b: phiW = h @ phi_w2 + b2.
// ---------------------------------------------------------------------------
__global__ __launch_bounds__(128) void k_phi2(
    const float* __restrict__ phiH,
    const float* __restrict__ w2, const float* __restrict__ b2,
    float* __restrict__ phiW){
    __shared__ float hL[SS];
    __shared__ float part[4][32];
    int t = threadIdx.x;
    hL[t] = phiH[t];
    __syncthreads();
    int c  = blockIdx.x*32 + (t & 31);
    int kk = t >> 5;
    float acc = 0.0f;
    int sbase = kk * 32;
    #pragma unroll 8
    for (int s = 0; s < 32; s++)
        acc = fmaf(hL[sbase + s], w2[(sbase + s)*3*SS + c], acc);
    part[kk][t & 31] = acc;
    __syncthreads();
    if (t < 32){
        int cc = blockIdx.x*32 + t;
        phiW[cc] = b2[cc] + part[0][t] + part[1][t] + part[2][t] + part[3][t];
    }
}

// ---------------------------------------------------------------------------
// Kernel 2: per-node edge processing (unchanged — round-0 proven).
// ---------------------------------------------------------------------------
__global__ __launch_bounds__(128) void k_edge(
    const float* __restrict__ evd, const float* __restrict__ elen,
    const int* __restrict__ node_from,
    const float* __restrict__ filt_w, const float* __restrict__ filt_b,
    const float* __restrict__ phiW,
    float* __restrict__ state, float* __restrict__ sv){
    __shared__ float rS[DEG];
    __shared__ float mcL[DEG];
    __shared__ float frL[DEG];
    __shared__ float eV[DEG][3];
    __shared__ float rbfL[DEG][NRBF];
    __shared__ float invD;
    int n = blockIdx.x;
    int t = threadIdx.x;

    if (t < DEG){
        int e = n*DEG + t;
        float x = evd[3*e+0], y = evd[3*e+1], z = evd[3*e+2];
        float r = sqrtf(x*x + y*y + z*z);
        float len  = elen[e];
        float mask = (fabsf(len) <= RC) ? 1.0f : 0.0f;
        float cut  = (r < RC) ? 0.5f*(cosf(PI_F*r*(1.0f/RC)) + 1.0f) : 0.0f;
        rS[t]  = fmaxf(r, 1e-12f);
        mcL[t] = mask * cut;
        frL[t] = mask * r * r;
        eV[t][0] = x; eV[t][1] = y; eV[t][2] = z;
    }
    __syncthreads();
    for (int idx = t; idx < DEG*NRBF; idx += 128){
        int e = idx / NRBF, k = idx % NRBF;
        float rs = rS[e];
        rbfL[e][k] = sinf((float)(k+1) * (PI_F/RC) * rs) / rs;
    }
    if (t == 0){
        float s = 0.0f;
        for (int e = 0; e < DEG; e++) s += frL[e];
        float fbn = sqrtf(s);
        invD = (fbn > 0.0f) ? 1.0f/fbn : 1.0f;
    }
    __syncthreads();

    int gc1 = SS + t;
    int gc2 = 2*SS + t;
    float fw1[NRBF], fw2[NRBF];
    #pragma unroll
    for (int k = 0; k < NRBF; k++){
        fw1[k] = filt_w[k*(3*SS) + gc1];
        fw2[k] = filt_w[k*(3*SS) + gc2];
    }
    float fb1 = filt_b[gc1], fb2 = filt_b[gc2];
    float ph1 = phiW[gc1],   ph2 = phiW[gc2];
    float iD  = invD;
    int   s3  = t % 3;

    float acc1 = 0.0f, acc2 = 0.0f;
    for (int e = 0; e < DEG; e++){
        float mc = mcL[e];
        if (mc == 0.0f) continue;
        const float4* rv = (const float4*)(&rbfL[e][0]);
        float4 r0 = rv[0], r1 = rv[1], r2 = rv[2], r3 = rv[3], r4 = rv[4];
        float rr[20] = {r0.x,r0.y,r0.z,r0.w, r1.x,r1.y,r1.z,r1.w,
                        r2.x,r2.y,r2.z,r2.w, r3.x,r3.y,r3.z,r3.w,
                        r4.x,r4.y,r4.z,r4.w};
        float w1 = fb1, w2 = fb2;
        #pragma unroll
        for (int k = 0; k < NRBF; k++){
            w1 = fmaf(rr[k], fw1[k], w1);
            w2 = fmaf(rr[k], fw2[k], w2);
        }
        acc1 = fmaf(ph1*mc, w1, acc1);
        acc2 = fmaf(ph2*mc*eV[e][s3]*iD, w2, acc2);
    }
    int nf = node_from[n*DEG];
    state[nf*SS + t] = acc1;
    sv[nf*SS + t]    = acc2;
}

// ---------------------------------------------------------------------------
// Kernel 3: per-node update. NB=16 nodes per 512-thread block.
// Thread = (channel ch = t&127, node-quad sub = t>>7); each thread keeps the
// proven round-0/4 inner loop over its 4 nodes. The 4 quads traverse the SAME
// weight-address stream between the same barriers -> waves 2..7 hit L1 behind
// the lead wave-pair: per-block L2 weight traffic ~384KB instead of 4x384KB
// (round-4 counters showed the L2 weight stream at ~18.5 TB/s was the wall).
// #pragma unroll batches 8 weight loads per group for MLP (VGPR=36 showed
// the compiler was holding only ~2 loads in flight).
// ---------------------------------------------------------------------------
__global__ __launch_bounds__(512) void k_update(
    const float* __restrict__ state, const float* __restrict__ sv,
    const float* __restrict__ u_w, const float* __restrict__ v_w,
    const float* __restrict__ upd_w1, const float* __restrict__ upd_b1,
    const float* __restrict__ upd_w2, const float* __restrict__ upd_b2,
    const int* __restrict__ ngi, float* __restrict__ gs){
    __shared__ __align__(16) float svT[SS][NB];     // [s][node] 8KB
    __shared__ __align__(16) float xT[2*SS][NB];    // [i][node] 16KB: i<SS Vnorm, i>=SS state
    __shared__ __align__(16) float h2T[SS][NB];     // 8KB
    __shared__ float red[8][4];                     // [wave][b] UV partials
    __shared__ float dL[NB];
    int t   = threadIdx.x;
    int ch  = t & 127;       // output channel
    int sub = t >> 7;        // node-quad 0..3
    int n0  = blockIdx.x * NB;

    for (int idx = t; idx < NB*SS; idx += TPB){
        int b = idx >> 7, s = idx & (SS-1);
        svT[s][b]   = sv[(n0+b)*SS + s];
        xT[SS+s][b] = state[(n0+b)*SS + s];
    }
    __syncthreads();

    // ---- loop1: U = sv@u_w, V = sv@v_w for channel ch, 4 nodes
    float accU[4], accV[4];
    #pragma unroll
    for (int b = 0; b < 4; b++){ accU[b]=0.f; accV[b]=0.f; }
    #pragma unroll 4
    for (int s = 0; s < SS; s++){
        float wu = u_w[s*SS + ch];
        float wv = v_w[s*SS + ch];
        float4 s03 = *((const float4*)(&svT[s][sub*4]));
        float svv[4] = {s03.x,s03.y,s03.z,s03.w};
        #pragma unroll
        for (int b = 0; b < 4; b++){
            accU[b] = fmaf(svv[b], wu, accU[b]);
            accV[b] = fmaf(svv[b], wv, accV[b]);
        }
    }

    int lane = t & 63, wid = t >> 6;   // wid 0..7; waves {2sub, 2sub+1} cover ch 0..63 / 64..127
    #pragma unroll
    for (int b = 0; b < 4; b++){
        float p = accU[b]*accV[b];
        for (int off = 32; off; off >>= 1) p += __shfl_down(p, off);
        if (lane == 0) red[wid][b] = p;
    }
    {   // Vnorm = sqrt(V0^2+V1^2+V2^2) with V0=V1=V2 -> sqrt(3 v^2)
        float4 q0;
        q0.x = sqrtf(3.f*accV[0]*accV[0]); q0.y = sqrtf(3.f*accV[1]*accV[1]);
        q0.z = sqrtf(3.f*accV[2]*accV[2]); q0.w = sqrtf(3.f*accV[3]*accV[3]);
        ((float4*)(&xT[ch][0]))[sub] = q0;
    }
    __syncthreads();
    if (t < NB) dL[t] = red[2*(t>>2)][t&3] + red[2*(t>>2)+1][t&3];

    // ---- loop2: h = silu(x @ upd_w1 + b1), x = [Vnorm, state] (2S inputs)
    float accH[4];
    #pragma unroll
    for (int b = 0; b < 4; b++) accH[b] = 0.f;
    #pragma unroll 8
    for (int i = 0; i < 2*SS; i++){
        float w = upd_w1[i*SS + ch];
        float4 x03 = *((const float4*)(&xT[i][sub*4]));
        float xv[4] = {x03.x,x03.y,x03.z,x03.w};
        #pragma unroll
        for (int b = 0; b < 4; b++) accH[b] = fmaf(xv[b], w, accH[b]);
    }
    float b1v = upd_b1[ch];
    {
        float4 q0;
        q0.x = silu_f(accH[0]+b1v); q0.y = silu_f(accH[1]+b1v);
        q0.z = silu_f(accH[2]+b1v); q0.w = silu_f(accH[3]+b1v);
        ((float4*)(&h2T[ch][0]))[sub] = q0;
    }
    __syncthreads();

    // ---- loop3: a_sv, a_ss channels of h @ upd_w2
    float a1[4], a2[4];
    #pragma unroll
    for (int b = 0; b < 4; b++){ a1[b]=0.f; a2[b]=0.f; }
    #pragma unroll 4
    for (int j = 0; j < SS; j++){
        float w1 = upd_w2[j*3*SS + SS   + ch];   // a_sv channel
        float w2 = upd_w2[j*3*SS + 2*SS + ch];   // a_ss channel
        float4 h03 = *((const float4*)(&h2T[j][sub*4]));
        float hv[4] = {h03.x,h03.y,h03.z,h03.w};
        #pragma unroll
        for (int b = 0; b < 4; b++){
            a1[b] = fmaf(hv[b], w1, a1[b]);
            a2[b] = fmaf(hv[b], w2, a2[b]);
        }
    }
    float bsv = upd_b2[SS+ch], bss = upd_b2[2*SS+ch];
    #pragma unroll
    for (int b = 0; b < 4; b++){
        float ns = (a2[b] + bss) + 3.0f*dL[sub*4+b]*(a1[b] + bsv);
        int g = ngi[n0 + sub*4 + b];
        atomicAdd(&gs[g*SS + ch], ns);
    }
}

// ---------------------------------------------------------------------------
// Kernel 4: readout per graph
// ---------------------------------------------------------------------------
__global__ __launch_bounds__(128) void k_out(
    const float* __restrict__ gs,
    const float* __restrict__ w1, const float* __restrict__ b1,
    const float* __restrict__ w2, const float* __restrict__ b2,
    float* __restrict__ out){
    __shared__ float gsL[SS];
    __shared__ float red[2];
    int g = blockIdx.x, t = threadIdx.x;
    gsL[t] = gs[g*SS + t];
    __syncthreads();
    float acc = b1[t];
    #pragma unroll 4
    for (int s = 0; s < SS; s++) acc = fmaf(gsL[s], w1[s*SS + t], acc);
    float p = silu_f(acc) * w2[t];
    for (int off = 32; off; off >>= 1) p += __shfl_down(p, off);
    if ((t & 63) == 0) red[t >> 6] = p;
    __syncthreads();
    if (t == 0) out[g] = red[0] + red[1] + b2[0];
}

extern "C" void kernel_launch(void* const* d_in, const int* in_sizes, int n_in,
                              void* d_out, int out_size, void* d_ws, size_t ws_size,
                              hipStream_t stream) {
    const float* evd     = (const float*)d_in[0];
    const float* elen    = (const float*)d_in[1];
    const int*   nfrom   = (const int*)  d_in[2];
    const int*   ngi     = (const int*)  d_in[3];
    // d_in[4] = num_graphs (device scalar) — G=64 fixed by setup
    const float* emb0    = (const float*)d_in[5];
    const float* phi_w1  = (const float*)d_in[6];
    const float* phi_b1  = (const float*)d_in[7];
    const float* phi_w2  = (const float*)d_in[8];
    const float* phi_b2  = (const float*)d_in[9];
    const float* filt_w  = (const float*)d_in[10];
    const float* filt_b  = (const float*)d_in[11];
    const float* u_w     = (const float*)d_in[12];
    const float* v_w     = (const float*)d_in[13];
    const float* upd_w1  = (const float*)d_in[14];
    const float* upd_b1  = (const float*)d_in[15];
    const float* upd_w2  = (const float*)d_in[16];
    const float* upd_b2  = (const float*)d_in[17];
    const float* out_w1  = (const float*)d_in[18];
    const float* out_b1  = (const float*)d_in[19];
    const float* out_w2  = (const float*)d_in[20];
    const float* out_b2  = (const float*)d_in[21];

    float* ws    = (float*)d_ws;
    float* phiW  = ws;                       // 384 (pad to 512)
    float* state = ws + 512;                 // N*S
    float* sv    = state + NN*SS;            // N*S
    float* gs    = sv + NN*SS;               // G*S
    float* phiH  = gs + GG*SS;               // 128

    k_phi1<<<1, 256, 0, stream>>>(emb0, phi_w1, phi_b1, phiH, gs);
    k_phi2<<<12, 128, 0, stream>>>(phiH, phi_w2, phi_b2, phiW);
    k_edge<<<NN, 128, 0, stream>>>(evd, elen, nfrom, filt_w, filt_b, phiW, state, sv);
    k_update<<<NN/NB, TPB, 0, stream>>>(state, sv, u_w, v_w,
                                        upd_w1, upd_b1, upd_w2, upd_b2, ngi, gs);
    k_out<<<GG, 128, 0, stream>>>(gs, out_w1, out_b1, out_w2, out_b2, (float*)d_out);
}